// Round 1
// baseline (739.459 us; speedup 1.0000x reference)
//
#include <hip/hip_runtime.h>
#include <math.h>

// Problem constants
#define KK 4096          // N == M == K
#define BATCH 4
#define NF 64            // feature dim
#define POS_MARGIN 0.1f
#define NEG_MARGIN 1.4f
#define LOG_SCALE 10.0f

// Tiling
#define BN 128                          // rows (pc index n) per block
#define BMT 128                         // cols (img index m) per tile
#define NCHUNK 4                        // m-chunks across grid
#define CHUNK_COLS (KK / NCHUNK)        // 1024 cols per block
#define MT_PER_BLOCK (CHUNK_COLS / BMT) // 8 tiles
#define NSTRIP (KK / BN)                // 32 row strips

// ws layout (float offsets)
// colPartials: [BATCH][NSTRIP][KK][4] = (Mp,Sp,Mn,Sn) per (b,strip,m)
// rowPartials: [BATCH][KK][NCHUNK][4]
// rsum[64], csum[64]
#define COLP_OFF 0ull
#define COLP_SZ ((size_t)BATCH * NSTRIP * KK * 4)
#define ROWP_OFF (COLP_OFF + COLP_SZ)
#define ROWP_SZ ((size_t)BATCH * KK * NCHUNK * 4)
#define NRBLK 64
#define NCBLK 64
#define RSUM_OFF (ROWP_OFF + ROWP_SZ)
#define CSUM_OFF (RSUM_OFF + NRBLK)

// -------------------------------------------------------------------------
// Fused: cross-GEMM (fp32 VALU) + dists + online row/col (max,sum) partials
// grid.x = BATCH * NSTRIP * NCHUNK, block = 256
// -------------------------------------------------------------------------
__launch_bounds__(256, 2)
__global__ void fused_main(const float* __restrict__ img,
                           const float* __restrict__ pc,
                           const float* __restrict__ dmap,
                           float* __restrict__ dists,
                           float* __restrict__ wsf) {
    __shared__ float As[NF][BN];    // pc tile  [f][n_local]
    __shared__ float Bs[NF][BMT];   // img tile [f][m_local]
    __shared__ float red[16][BMT];  // cross-ty reduction scratch
    __shared__ float pcsqS[BN], imsqS[BMT], colMaxS[BMT], colMinS[BMT];

    const int blk = blockIdx.x;
    const int b = blk / (NSTRIP * NCHUNK);
    const int r2 = blk % (NSTRIP * NCHUNK);
    const int strip = r2 / NCHUNK;
    const int chunk = r2 % NCHUNK;
    const int n0 = strip * BN;
    const int m0 = chunk * CHUNK_COLS;

    const int t = threadIdx.x;
    const int tx = t & 15;   // col group (16)
    const int ty = t >> 4;   // row group (16)

    const float* pcb = pc + (size_t)b * NF * KK;
    const float* imb = img + (size_t)b * NF * KK;
    const float* dmb = dmap + (size_t)b * KK * KK;
    float* dob = dists + (size_t)b * KK * KK;

    // ---- stage pc strip: 64x128 floats (2048 float4 / 256 thr = 8 each)
    #pragma unroll
    for (int i = 0; i < 8; ++i) {
        int l4 = i * 256 + t;
        int f = l4 >> 5;       // 32 float4 per row of 128
        int j4 = l4 & 31;
        float4 v = *(const float4*)(pcb + (size_t)f * KK + n0 + j4 * 4);
        *(float4*)&As[f][j4 * 4] = v;
    }
    __syncthreads();
    if (t < BN) {  // pc_sq per local row
        float s = 0.f;
        for (int f = 0; f < NF; ++f) { float x = As[f][t]; s += x * x; }
        pcsqS[t] = s;
    }

    // per-thread online row state over this thread's own columns
    float Mp[8], Sp[8], Mn[8], Sn[8];
    #pragma unroll
    for (int i = 0; i < 8; ++i) { Mp[i] = 0.f; Sp[i] = 0.f; Mn[i] = 0.f; Sn[i] = 0.f; }

    for (int mt = 0; mt < MT_PER_BLOCK; ++mt) {
        const int m0t = m0 + mt * BMT;
        __syncthreads();  // previous-iteration consumers of Bs/imsq/red done (also pcsq visible)

        // ---- stage img tile
        #pragma unroll
        for (int i = 0; i < 8; ++i) {
            int l4 = i * 256 + t;
            int f = l4 >> 5;
            int j4 = l4 & 31;
            float4 v = *(const float4*)(imb + (size_t)f * KK + m0t + j4 * 4);
            *(float4*)&Bs[f][j4 * 4] = v;
        }
        __syncthreads();
        if (t < BMT) {  // im_sq per local col
            float s = 0.f;
            for (int f = 0; f < NF; ++f) { float x = Bs[f][t]; s += x * x; }
            imsqS[t] = s;
        }

        // ---- fp32 register GEMM: 8x8 micro-tile (rows ty*4+{0..3} and 64+ty*4+{0..3})
        float acc[8][8];
        #pragma unroll
        for (int i = 0; i < 8; ++i)
            #pragma unroll
            for (int j = 0; j < 8; ++j) acc[i][j] = 0.f;

        #pragma unroll 8
        for (int f = 0; f < NF; ++f) {
            float4 a0 = *(const float4*)&As[f][ty * 4];
            float4 a1 = *(const float4*)&As[f][64 + ty * 4];
            float4 b0 = *(const float4*)&Bs[f][tx * 4];
            float4 b1 = *(const float4*)&Bs[f][64 + tx * 4];
            float a[8] = {a0.x, a0.y, a0.z, a0.w, a1.x, a1.y, a1.z, a1.w};
            float bb[8] = {b0.x, b0.y, b0.z, b0.w, b1.x, b1.y, b1.z, b1.w};
            #pragma unroll
            for (int i = 0; i < 8; ++i)
                #pragma unroll
                for (int j = 0; j < 8; ++j) acc[i][j] = fmaf(a[i], bb[j], acc[i][j]);
        }
        __syncthreads();  // imsqS ready for everyone; GEMM reads of Bs done

        // ---- epilogue: dists, then overwrite acc with signed logit e
        //  e >= 0: pos_logit = e (mask=1); e <= 0: neg_logit = -e (mask=0)
        #pragma unroll
        for (int rg = 0; rg < 2; ++rg) {
            #pragma unroll
            for (int ii = 0; ii < 4; ++ii) {
                const int i = rg * 4 + ii;
                const int nloc = rg * 64 + ty * 4 + ii;
                const int n = n0 + nloc;
                const float psq = pcsqS[nloc];
                const size_t rowbase = (size_t)n * KK + m0t;
                #pragma unroll
                for (int cg = 0; cg < 2; ++cg) {
                    const int cl0 = cg * 64 + tx * 4;
                    float4 dm4 = *(const float4*)(dmb + rowbase + cl0);
                    float dmv[4] = {dm4.x, dm4.y, dm4.z, dm4.w};
                    #pragma unroll
                    for (int jj = 0; jj < 4; ++jj) {
                        const int j = cg * 4 + jj;
                        float d2 = fmaf(-2.f, acc[i][j], psq + imsqS[cl0 + jj]);
                        float d = sqrtf(fmaxf(d2, 1e-12f));
                        dob[rowbase + cl0 + jj] = d;  // scalar store: dists base = d_out+1 (4B aligned only)
                        float rp = fmaxf(d - POS_MARGIN, 0.f);
                        float rn = fmaxf(NEG_MARGIN - d, 0.f);
                        float ep = LOG_SCALE * rp * rp;
                        float en = -(LOG_SCALE * rn * rn);
                        acc[i][j] = (dmv[jj] <= 1.0f) ? ep : en;
                    }
                }
            }
        }

        // ---- column stats (tile-complete: each column seen exactly once per block)
        float cmx[8], cmn[8];
        #pragma unroll
        for (int j = 0; j < 8; ++j) {
            float mx = acc[0][j], mn = acc[0][j];
            #pragma unroll
            for (int i = 1; i < 8; ++i) { mx = fmaxf(mx, acc[i][j]); mn = fminf(mn, acc[i][j]); }
            cmx[j] = mx; cmn[j] = mn;
        }
        #pragma unroll
        for (int cg = 0; cg < 2; ++cg)
            *(float4*)&red[ty][cg * 64 + tx * 4] =
                make_float4(cmx[cg * 4], cmx[cg * 4 + 1], cmx[cg * 4 + 2], cmx[cg * 4 + 3]);
        __syncthreads();
        if (t < BMT) {
            float v = red[0][t];
            #pragma unroll
            for (int s = 1; s < 16; ++s) v = fmaxf(v, red[s][t]);
            colMaxS[t] = v;
        }
        __syncthreads();
        #pragma unroll
        for (int cg = 0; cg < 2; ++cg)
            *(float4*)&red[ty][cg * 64 + tx * 4] =
                make_float4(cmn[cg * 4], cmn[cg * 4 + 1], cmn[cg * 4 + 2], cmn[cg * 4 + 3]);
        __syncthreads();
        if (t < BMT) {
            float v = red[0][t];
            #pragma unroll
            for (int s = 1; s < 16; ++s) v = fminf(v, red[s][t]);
            colMinS[t] = v;
        }
        __syncthreads();

        // positive col sums: exp(relu(e) - relu(colmax))
        #pragma unroll
        for (int cg = 0; cg < 2; ++cg) {
            float s4[4];
            #pragma unroll
            for (int jj = 0; jj < 4; ++jj) {
                int j = cg * 4 + jj;
                int c = cg * 64 + tx * 4 + jj;
                float M = fmaxf(colMaxS[c], 0.f);
                float s = 0.f;
                #pragma unroll
                for (int i = 0; i < 8; ++i) s += __expf(fmaxf(acc[i][j], 0.f) - M);
                s4[jj] = s;
            }
            *(float4*)&red[ty][cg * 64 + tx * 4] = make_float4(s4[0], s4[1], s4[2], s4[3]);
        }
        __syncthreads();
        if (t < BMT) {
            float s = 0.f;
            #pragma unroll
            for (int ss = 0; ss < 16; ++ss) s += red[ss][t];
            float M = fmaxf(colMaxS[t], 0.f);
            size_t cidx = (((size_t)b * NSTRIP + strip) * KK + (size_t)(m0t + t)) * 4;
            *(float2*)&wsf[COLP_OFF + cidx] = make_float2(M, s);
        }
        __syncthreads();

        // negative col sums: exp(relu(-e) - relu(-colmin))
        #pragma unroll
        for (int cg = 0; cg < 2; ++cg) {
            float s4[4];
            #pragma unroll
            for (int jj = 0; jj < 4; ++jj) {
                int j = cg * 4 + jj;
                int c = cg * 64 + tx * 4 + jj;
                float M = fmaxf(-colMinS[c], 0.f);
                float s = 0.f;
                #pragma unroll
                for (int i = 0; i < 8; ++i) s += __expf(fmaxf(-acc[i][j], 0.f) - M);
                s4[jj] = s;
            }
            *(float4*)&red[ty][cg * 64 + tx * 4] = make_float4(s4[0], s4[1], s4[2], s4[3]);
        }
        __syncthreads();
        if (t < BMT) {
            float s = 0.f;
            #pragma unroll
            for (int ss = 0; ss < 16; ++ss) s += red[ss][t];
            float M = fmaxf(-colMinS[t], 0.f);
            size_t cidx = (((size_t)b * NSTRIP + strip) * KK + (size_t)(m0t + t)) * 4;
            *(float2*)&wsf[COLP_OFF + cidx + 2] = make_float2(M, s);
        }

        // ---- row online update (per-thread, own 8 columns only; no shuffles here)
        #pragma unroll
        for (int i = 0; i < 8; ++i) {
            float mx = acc[i][0], mn = acc[i][0];
            #pragma unroll
            for (int j = 1; j < 8; ++j) { mx = fmaxf(mx, acc[i][j]); mn = fminf(mn, acc[i][j]); }
            float Mnew = fmaxf(Mp[i], fmaxf(mx, 0.f));
            float s = 0.f;
            #pragma unroll
            for (int j = 0; j < 8; ++j) s += __expf(fmaxf(acc[i][j], 0.f) - Mnew);
            Sp[i] = Sp[i] * __expf(Mp[i] - Mnew) + s;
            Mp[i] = Mnew;
            float Mnn = fmaxf(Mn[i], fmaxf(-mn, 0.f));
            float sn = 0.f;
            #pragma unroll
            for (int j = 0; j < 8; ++j) sn += __expf(fmaxf(-acc[i][j], 0.f) - Mnn);
            Sn[i] = Sn[i] * __expf(Mn[i] - Mnn) + sn;
            Mn[i] = Mnn;
        }
    }

    // ---- merge row state across the 16 tx lanes (same-wave 16-lane groups)
    #pragma unroll
    for (int i = 0; i < 8; ++i) {
        float M = Mp[i], S = Sp[i];
        #pragma unroll
        for (int k = 1; k < 16; k <<= 1) {
            float Mo = __shfl_xor(M, k);
            float So = __shfl_xor(S, k);
            float Mx = fmaxf(M, Mo);
            S = S * __expf(M - Mx) + So * __expf(Mo - Mx);
            M = Mx;
        }
        Mp[i] = M; Sp[i] = S;
        M = Mn[i]; S = Sn[i];
        #pragma unroll
        for (int k = 1; k < 16; k <<= 1) {
            float Mo = __shfl_xor(M, k);
            float So = __shfl_xor(S, k);
            float Mx = fmaxf(M, Mo);
            S = S * __expf(M - Mx) + So * __expf(Mo - Mx);
            M = Mx;
        }
        Mn[i] = M; Sn[i] = S;
    }
    if (tx == 0) {
        #pragma unroll
        for (int i = 0; i < 8; ++i) {
            int nloc = (i >> 2) * 64 + ty * 4 + (i & 3);
            int n = n0 + nloc;
            size_t idx = ROWP_OFF + (((size_t)b * KK + n) * NCHUNK + chunk) * 4;
            wsf[idx + 0] = Mp[i];
            wsf[idx + 1] = Sp[i];
            wsf[idx + 2] = Mn[i];
            wsf[idx + 3] = Sn[i];
        }
    }
}

// -------------------------------------------------------------------------
// Merge row partials -> softplus -> per-block sums
// -------------------------------------------------------------------------
__global__ void reduce_rows(const float* __restrict__ wsf, float* __restrict__ wout) {
    __shared__ float sh[4];
    const int t = threadIdx.x;
    const int gid = blockIdx.x * 256 + t;  // b*KK + n
    const float* rp = wsf + ROWP_OFF + (size_t)gid * (NCHUNK * 4);
    float mP = 0.f, mN = 0.f;
    #pragma unroll
    for (int c = 0; c < NCHUNK; ++c) {
        mP = fmaxf(mP, rp[c * 4 + 0]);
        mN = fmaxf(mN, rp[c * 4 + 2]);
    }
    float sP = 0.f, sN = 0.f;
    #pragma unroll
    for (int c = 0; c < NCHUNK; ++c) {
        sP += rp[c * 4 + 1] * __expf(rp[c * 4 + 0] - mP);
        sN += rp[c * 4 + 3] * __expf(rp[c * 4 + 2] - mN);
    }
    float x = (mP + logf(sP)) + (mN + logf(sN));
    float v = fmaxf(x, 0.f) + log1pf(__expf(-fabsf(x)));  // softplus
    #pragma unroll
    for (int k = 32; k >= 1; k >>= 1) v += __shfl_xor(v, k);
    if ((t & 63) == 0) sh[t >> 6] = v;
    __syncthreads();
    if (t == 0) wout[blockIdx.x] = sh[0] + sh[1] + sh[2] + sh[3];
}

// -------------------------------------------------------------------------
// Merge col partials (NSTRIP per column) -> softplus -> per-block sums
// -------------------------------------------------------------------------
__global__ void reduce_cols(const float* __restrict__ wsf, float* __restrict__ wout) {
    __shared__ float sh[4];
    const int t = threadIdx.x;
    const int gid = blockIdx.x * 256 + t;  // b*KK + m
    const int b = gid >> 12;
    const int m = gid & (KK - 1);
    float mP = 0.f, mN = 0.f;
    for (int s = 0; s < NSTRIP; ++s) {
        float4 v = *(const float4*)&wsf[COLP_OFF + (((size_t)b * NSTRIP + s) * KK + m) * 4];
        mP = fmaxf(mP, v.x);
        mN = fmaxf(mN, v.z);
    }
    float sP = 0.f, sN = 0.f;
    for (int s = 0; s < NSTRIP; ++s) {
        float4 v = *(const float4*)&wsf[COLP_OFF + (((size_t)b * NSTRIP + s) * KK + m) * 4];
        sP += v.y * __expf(v.x - mP);
        sN += v.w * __expf(v.z - mN);
    }
    float x = (mP + logf(sP)) + (mN + logf(sN));
    float v = fmaxf(x, 0.f) + log1pf(__expf(-fabsf(x)));
    #pragma unroll
    for (int k = 32; k >= 1; k >>= 1) v += __shfl_xor(v, k);
    if ((t & 63) == 0) sh[t >> 6] = v;
    __syncthreads();
    if (t == 0) wout[blockIdx.x] = sh[0] + sh[1] + sh[2] + sh[3];
}

// -------------------------------------------------------------------------
// Final scalar: loss = (sum softplus_rows + sum softplus_cols) / (10 * B * K)
// -------------------------------------------------------------------------
__global__ void finalize(const float* __restrict__ wsf, float* __restrict__ out) {
    __shared__ float sh[2];
    const int t = threadIdx.x;  // 128 threads
    float v = (t < NRBLK) ? wsf[RSUM_OFF + t] : wsf[CSUM_OFF + (t - NRBLK)];
    #pragma unroll
    for (int k = 32; k >= 1; k >>= 1) v += __shfl_xor(v, k);
    if ((t & 63) == 0) sh[t >> 6] = v;
    __syncthreads();
    if (t == 0) out[0] = (sh[0] + sh[1]) * (1.0f / (LOG_SCALE * BATCH * KK));
}

extern "C" void kernel_launch(void* const* d_in, const int* in_sizes, int n_in,
                              void* d_out, int out_size, void* d_ws, size_t ws_size,
                              hipStream_t stream) {
    const float* img = (const float*)d_in[0];   // img_features [B,F,K]
    const float* pc = (const float*)d_in[1];    // pc_features  [B,F,K]
    const float* dmap = (const float*)d_in[2];  // distance_map [B,K,K]
    float* out = (float*)d_out;                 // [loss, dists...]
    float* wsf = (float*)d_ws;
    float* dists = out + 1;

    fused_main<<<dim3(BATCH * NSTRIP * NCHUNK), dim3(256), 0, stream>>>(img, pc, dmap, dists, wsf);
    reduce_rows<<<dim3(NRBLK), dim3(256), 0, stream>>>(wsf, wsf + RSUM_OFF);
    reduce_cols<<<dim3(NCBLK), dim3(256), 0, stream>>>(wsf, wsf + CSUM_OFF);
    finalize<<<dim3(1), dim3(128), 0, stream>>>(wsf, out);
}

// Round 5
// 575.167 us; speedup vs baseline: 1.2856x; 1.2856x over previous
//
#include <hip/hip_runtime.h>
#include <math.h>

#define KK 4096
#define BATCH 4
#define NF 64
#define MT 4                 // m-tiles (128 wide) per block
typedef unsigned int uint32;
typedef __bf16 v8bf __attribute__((ext_vector_type(8)));
typedef float v4f __attribute__((ext_vector_type(4)));

// ---- workspace layout ----
// bytes [0,8MB): bf16 feature arrays, each [B][K][64], 2MB apiece
#define PCT_HI_B 0ull
#define PCT_LO_B (2ull<<20)
#define IMT_HI_B (4ull<<20)
#define IMT_LO_B (6ull<<20)
#define FEAT_STRIDE_B (512ull<<10)      // per-batch bytes: 4096*64*2
// float offsets
#define PSQ_OFF 2097152ull              // [B][K] fp32
#define ISQ_OFF 2113536ull              // [B][K] fp32
#define ROWP_OFF 2129920ull             // [B][8 chunk][2 wc][4096 n] float4 = 4MB
#define COLP_OFF 3178496ull             // [B][32 strip][2 wr][4096 m] float4 = 16MB
#define SUMS_OFF 7372800ull             // 128 floats
// total ~29.5 MB

#define GLDS(gp, lp) __builtin_amdgcn_global_load_lds((const __attribute__((address_space(1))) uint32*)(gp), (__attribute__((address_space(3))) uint32*)(lp), 16, 0, 0)

// -------------------------------------------------------------------------
// prep: transpose+convert features to bf16 hi/lo [B][K][64], plus fp32 sq
// grid 256 (= B * K/64), block 256
// -------------------------------------------------------------------------
__global__ __launch_bounds__(256) void prep(const float* __restrict__ img,
                                            const float* __restrict__ pc,
                                            float* __restrict__ wsf) {
    __shared__ float Ts[64][65];
    const int t = threadIdx.x;
    const int b = blockIdx.x >> 6;
    const int k0 = (blockIdx.x & 63) << 6;
    char* wb = (char*)wsf;

    for (int s = 0; s < 2; ++s) {
        const float* src = s ? pc : img;
        char* hiB = wb + (s ? PCT_HI_B : IMT_HI_B) + (size_t)b * FEAT_STRIDE_B;
        char* loB = wb + (s ? PCT_LO_B : IMT_LO_B) + (size_t)b * FEAT_STRIDE_B;
        float* sqout = wsf + (s ? PSQ_OFF : ISQ_OFF) + b * 4096 + k0;

        #pragma unroll
        for (int i = 0; i < 4; ++i) {
            int id = t + i * 256;
            int f = id >> 4, q = id & 15;
            float4 v = *(const float4*)(src + ((size_t)b * NF + f) * KK + k0 + q * 4);
            Ts[f][q * 4 + 0] = v.x; Ts[f][q * 4 + 1] = v.y;
            Ts[f][q * 4 + 2] = v.z; Ts[f][q * 4 + 3] = v.w;
        }
        __syncthreads();

        const int kl = t >> 2, part = t & 3;
        float sq = 0.f;
        uint32 hw[8] = {0,0,0,0,0,0,0,0}, lw[8] = {0,0,0,0,0,0,0,0};
        #pragma unroll
        for (int ff = 0; ff < 16; ++ff) {
            float x = Ts[part * 16 + ff][kl];
            sq = fmaf(x, x, sq);
            uint32 u = __float_as_uint(x);
            uint32 hr = (u + 0x7FFFu + ((u >> 16) & 1u)) >> 16;
            float hf = __uint_as_float(hr << 16);
            float xl = x - hf;
            uint32 ul = __float_as_uint(xl);
            uint32 lr = (ul + 0x7FFFu + ((ul >> 16) & 1u)) >> 16;
            hw[ff >> 1] |= (hr & 0xFFFFu) << ((ff & 1) * 16);
            lw[ff >> 1] |= (lr & 0xFFFFu) << ((ff & 1) * 16);
        }
        char* hp = hiB + (size_t)(k0 + kl) * 128 + part * 32;
        char* lp = loB + (size_t)(k0 + kl) * 128 + part * 32;
        *(uint4*)hp = make_uint4(hw[0], hw[1], hw[2], hw[3]);
        *((uint4*)hp + 1) = make_uint4(hw[4], hw[5], hw[6], hw[7]);
        *(uint4*)lp = make_uint4(lw[0], lw[1], lw[2], lw[3]);
        *((uint4*)lp + 1) = make_uint4(lw[4], lw[5], lw[6], lw[7]);

        sq += __shfl_xor(sq, 1);
        sq += __shfl_xor(sq, 2);
        if (part == 0) sqout[kl] = sq;
        __syncthreads();
    }
}

// -------------------------------------------------------------------------
// fused: MFMA cross-GEMM (bf16 hi/lo, 3 terms) + dists + online partials
// grid 1024 (= B * 32 strips * 8 chunks), block 256 (4 waves, 2x2)
// -------------------------------------------------------------------------
__device__ __forceinline__ void stageT(const char* g, char* l, int wid, int lane) {
    #pragma unroll
    for (int i = 0; i < 4; ++i) {
        int o = i * 4096 + wid * 1024 + lane * 16;
        int r = o >> 7, c = o & 127;
        GLDS(g + (size_t)r * 128 + (c ^ ((r & 7) << 4)), l + i * 4096 + wid * 1024);
    }
}

__device__ __forceinline__ v8bf ldfrag(const char* base, int row, int kbyte) {
    int off = row * 128 + (kbyte ^ ((row & 7) << 4));
    return *(const v8bf*)(base + off);
}

__global__ __launch_bounds__(256, 2) void fused_main(const float* __restrict__ dmap,
                                                     float* __restrict__ dists,
                                                     float* __restrict__ wsf) {
    __shared__ char As_hi[16384], As_lo[16384], Bs_hi[16384], Bs_lo[16384];
    const int t = threadIdx.x;
    const int lane = t & 63;
    const int wid = t >> 6;
    const int wr = wid >> 1, wc = wid & 1;
    const int low = lane & 15, lg = lane >> 4;

    const int blk = blockIdx.x;
    const int b = blk >> 8;
    const int r2 = blk & 255;
    const int strip = r2 >> 3;
    const int chunk = r2 & 7;
    const int n0 = strip * 128;
    const int m0 = chunk * (MT * 128);

    const char* wbc = (const char*)wsf;
    const char* pcHi = wbc + PCT_HI_B + (size_t)b * FEAT_STRIDE_B;
    const char* pcLo = wbc + PCT_LO_B + (size_t)b * FEAT_STRIDE_B;
    const char* imHi = wbc + IMT_HI_B + (size_t)b * FEAT_STRIDE_B;
    const char* imLo = wbc + IMT_LO_B + (size_t)b * FEAT_STRIDE_B;
    const float* dmb = dmap + (size_t)b * KK * KK;
    float* dob = dists + (size_t)b * KK * KK;

    // stage A (whole strip) and B tile 0
    stageT(pcHi + (size_t)n0 * 128, As_hi, wid, lane);
    stageT(pcLo + (size_t)n0 * 128, As_lo, wid, lane);
    stageT(imHi + (size_t)m0 * 128, Bs_hi, wid, lane);
    stageT(imLo + (size_t)m0 * 128, Bs_lo, wid, lane);

    // per-lane row sq (fp32, exact); base offset into dmap/dists
    float psqv[16];
    #pragma unroll
    for (int si = 0; si < 4; ++si)
        #pragma unroll
        for (int rg = 0; rg < 4; ++rg)
            psqv[si * 4 + rg] = wsf[PSQ_OFF + b * 4096 + n0 + wr * 64 + si * 16 + lg * 4 + rg];
    const uint32 robase = (uint32)(n0 + wr * 64 + lg * 4) * KK + m0 + wc * 64 + low;

    float Mrow = 0.f, SpRow = 0.f, SnRow = 0.f;  // online row-LSE state (owner lane)

    __syncthreads();  // staging (incl. GLDS, drained by vmcnt0) visible to all

    #pragma unroll 1
    for (int mt = 0; mt < MT; ++mt) {
        const int m0t = m0 + mt * 128;

        // prefetch dmap + im_sq for this tile into regs (latency hides under MFMA)
        float dm[4][4][4];
        #pragma unroll
        for (int si = 0; si < 4; ++si)
            #pragma unroll
            for (int rg = 0; rg < 4; ++rg) {
                uint32 ro = robase + ((uint32)(si * 16 + rg) << 12) + mt * 128;
                #pragma unroll
                for (int sj = 0; sj < 4; ++sj)
                    dm[si][sj][rg] = __builtin_nontemporal_load(dmb + ro + sj * 16);
            }
        float isqv[4];
        #pragma unroll
        for (int sj = 0; sj < 4; ++sj)
            isqv[sj] = wsf[ISQ_OFF + b * 4096 + m0t + wc * 64 + sj * 16 + low];

        // ---- MFMA: cross = Ah*Bh + Ah*Bl + Al*Bh over K=64 (2 ksteps) ----
        v4f acc[4][4];
        #pragma unroll
        for (int si = 0; si < 4; ++si)
            #pragma unroll
            for (int sj = 0; sj < 4; ++sj)
                acc[si][sj] = (v4f){0.f, 0.f, 0.f, 0.f};

        #pragma unroll
        for (int kk = 0; kk < 2; ++kk) {
            const int kb = kk * 64 + lg * 16;
            v8bf bh[4], bl[4];
            #pragma unroll
            for (int sj = 0; sj < 4; ++sj) {
                int rb = wc * 64 + sj * 16 + low;
                bh[sj] = ldfrag(Bs_hi, rb, kb);
                bl[sj] = ldfrag(Bs_lo, rb, kb);
            }
            #pragma unroll
            for (int si = 0; si < 4; ++si) {
                int ra = wr * 64 + si * 16 + low;
                v8bf ah = ldfrag(As_hi, ra, kb);
                v8bf al = ldfrag(As_lo, ra, kb);
                #pragma unroll
                for (int sj = 0; sj < 4; ++sj) {
                    acc[si][sj] = __builtin_amdgcn_mfma_f32_16x16x32_bf16(ah, bh[sj], acc[si][sj], 0, 0, 0);
                    acc[si][sj] = __builtin_amdgcn_mfma_f32_16x16x32_bf16(ah, bl[sj], acc[si][sj], 0, 0, 0);
                    acc[si][sj] = __builtin_amdgcn_mfma_f32_16x16x32_bf16(al, bh[sj], acc[si][sj], 0, 0, 0);
                }
            }
        }

        __syncthreads();  // #1: all waves' Bs reads done; dm/isq drained too

        // stage next B tile now; GLDS latency hides under the epilogue below,
        // drained by barrier #2's vmcnt(0)
        if (mt < MT - 1) {
            stageT(imHi + (size_t)(m0t + 128) * 128, Bs_hi, wid, lane);
            stageT(imLo + (size_t)(m0t + 128) * 128, Bs_lo, wid, lane);
        }

        // ---- pass A: dists + signed logit e (overwrite acc) ----
        // e >= 0: pos-classified, pos_logit = e,  neg_logit = 0
        // e <  0: neg-classified, pos_logit = 0,  neg_logit = -e (<= 19.6)
        #pragma unroll
        for (int si = 0; si < 4; ++si)
            #pragma unroll
            for (int rg = 0; rg < 4; ++rg) {
                uint32 ro = robase + ((uint32)(si * 16 + rg) << 12) + mt * 128;
                float ps = psqv[si * 4 + rg];
                #pragma unroll
                for (int sj = 0; sj < 4; ++sj) {
                    float c = acc[si][sj][rg];
                    float d2 = fmaf(-2.f, c, ps + isqv[sj]);
                    float d = sqrtf(fmaxf(d2, 1e-12f));
                    dob[ro + sj * 16] = d;
                    bool pos = dm[si][sj][rg] <= 1.0f;
                    float r = fmaxf(pos ? (d - 0.1f) : (1.4f - d), 0.f);
                    float l = (10.f * r) * r;
                    acc[si][sj][rg] = pos ? l : -l;
                }
            }

        // ---- pass B row: PER-ROW max (not wave max!) then exp-sums ----
        // (wave-max normalization underflowed every partial to 0 -> loss==0;
        //  per-row max guarantees the partial holding the row max has Sp>=1)
        #pragma unroll
        for (int si = 0; si < 4; ++si) {
            float mr[4];
            #pragma unroll
            for (int rg = 0; rg < 4; ++rg) {
                float m = 0.f;
                #pragma unroll
                for (int sj = 0; sj < 4; ++sj) m = fmaxf(m, acc[si][sj][rg]);
                mr[rg] = m;
            }
            #pragma unroll
            for (int k = 1; k < 16; k <<= 1)
                #pragma unroll
                for (int rg = 0; rg < 4; ++rg) mr[rg] = fmaxf(mr[rg], __shfl_xor(mr[rg], k));

            float sp[4] = {0,0,0,0}, sn[4] = {0,0,0,0}, cp[4] = {0,0,0,0};
            #pragma unroll
            for (int sj = 0; sj < 4; ++sj)
                #pragma unroll
                for (int rg = 0; rg < 4; ++rg) {
                    float e = acc[si][sj][rg];
                    bool pos = e >= 0.f;               // -0 lands pos: harmless (both branches exp(0))
                    float q = pos ? (e - mr[rg]) : (-e);
                    float tt = __expf(q);
                    float t0 = pos ? tt : 0.f;
                    sp[rg] += t0;
                    sn[rg] += tt - t0;
                    cp[rg] += pos ? 1.f : 0.f;
                }
            #pragma unroll
            for (int k = 1; k < 16; k <<= 1)
                #pragma unroll
                for (int rg = 0; rg < 4; ++rg) {
                    sp[rg] += __shfl_xor(sp[rg], k);
                    sn[rg] += __shfl_xor(sn[rg], k);
                    cp[rg] += __shfl_xor(cp[rg], k);
                }
            if ((low >> 2) == si) {  // owner lane for row (si, lg, rg=low&3)
                int rg = low & 3;
                float Mr = mr[rg];
                float Spt = sp[rg] + (64.f - cp[rg]) * __expf(-Mr);  // neg-classified: pos_logit=0
                float Snt = sn[rg] + cp[rg];                         // pos-classified: neg_logit=0
                float M2 = fmaxf(Mrow, Mr);
                SpRow = SpRow * __expf(Mrow - M2) + Spt * __expf(Mr - M2);
                SnRow += Snt;
                Mrow = M2;
            }
        }

        // ---- pass B col: PER-COLUMN max then exp-sums ----
        {
            float mc[4];
            #pragma unroll
            for (int sj = 0; sj < 4; ++sj) {
                float m = 0.f;
                #pragma unroll
                for (int si = 0; si < 4; ++si)
                    #pragma unroll
                    for (int rg = 0; rg < 4; ++rg) m = fmaxf(m, acc[si][sj][rg]);
                mc[sj] = m;
            }
            #pragma unroll
            for (int k = 16; k < 64; k <<= 1)
                #pragma unroll
                for (int sj = 0; sj < 4; ++sj) mc[sj] = fmaxf(mc[sj], __shfl_xor(mc[sj], k));

            float spc[4] = {0,0,0,0}, snc[4] = {0,0,0,0}, cpc[4] = {0,0,0,0};
            #pragma unroll
            for (int si = 0; si < 4; ++si)
                #pragma unroll
                for (int sj = 0; sj < 4; ++sj)
                    #pragma unroll
                    for (int rg = 0; rg < 4; ++rg) {
                        float e = acc[si][sj][rg];
                        bool pos = e >= 0.f;
                        float q = pos ? (e - mc[sj]) : (-e);
                        float tt = __expf(q);
                        float t0 = pos ? tt : 0.f;
                        spc[sj] += t0;
                        snc[sj] += tt - t0;
                        cpc[sj] += pos ? 1.f : 0.f;
                    }
            #pragma unroll
            for (int k = 16; k < 64; k <<= 1)
                #pragma unroll
                for (int sj = 0; sj < 4; ++sj) {
                    spc[sj] += __shfl_xor(spc[sj], k);
                    snc[sj] += __shfl_xor(snc[sj], k);
                    cpc[sj] += __shfl_xor(cpc[sj], k);
                }
            int sj = lg;  // owner: column m0t + wc*64 + lane (== sj*16+low)
            float Mc = mc[sj];
            float Sp = spc[sj] + (64.f - cpc[sj]) * __expf(-Mc);
            float Sn = snc[sj] + cpc[sj];
            int m = m0t + wc * 64 + lane;
            float4* cp4 = (float4*)(wsf + COLP_OFF) + (((size_t)b * 32 + strip) * 2 + wr) * KK + m;
            *cp4 = make_float4(Mc, Sp, Sn, 0.f);
        }

        if (mt < MT - 1) __syncthreads();  // #2: next Bs staged (vmcnt0) before next MFMA
    }

    // ---- final row partial write: each lane owns one row of the subtile ----
    {
        int si = low >> 2, rg = low & 3;
        int n = n0 + wr * 64 + si * 16 + lg * 4 + rg;
        float4* rp4 = (float4*)(wsf + ROWP_OFF) + (((size_t)b * 8 + chunk) * 2 + wc) * KK + n;
        *rp4 = make_float4(Mrow, SpRow, SnRow, 0.f);
    }
}

// -------------------------------------------------------------------------
// reduce: merge partials per row (16) / col (64) -> softplus -> block sums
// grid 128 (blocks 0-63 rows, 64-127 cols), block 256
// -------------------------------------------------------------------------
__global__ __launch_bounds__(256) void reduce_lse(const float* __restrict__ wsf,
                                                  float* __restrict__ sums) {
    __shared__ float sh[4];
    const int t = threadIdx.x;
    const int gid = blockIdx.x * 256 + t;
    const int region = gid >> 14;      // uniform per block
    const int idx = gid & 16383;
    const int b = idx >> 12;
    const int n = idx & 4095;
    const float4* p4 = (const float4*)(wsf + (region ? COLP_OFF : ROWP_OFF));
    const int cnt = region ? 64 : 16;
    const size_t base = (size_t)b * cnt * KK + n;
    float M = 0.f;
    for (int j = 0; j < cnt; ++j) M = fmaxf(M, p4[base + (size_t)j * KK].x);
    float Sp = 0.f, Sn = 0.f;
    for (int j = 0; j < cnt; ++j) {
        float4 v = p4[base + (size_t)j * KK];
        Sp += v.y * __expf(v.x - M);
        Sn += v.z;
    }
    float x = M + logf(Sp) + logf(Sn);
    float v = fmaxf(x, 0.f) + log1pf(__expf(-fabsf(x)));
    #pragma unroll
    for (int k = 1; k < 64; k <<= 1) v += __shfl_xor(v, k);
    if ((t & 63) == 0) sh[t >> 6] = v;
    __syncthreads();
    if (t == 0) sums[blockIdx.x] = sh[0] + sh[1] + sh[2] + sh[3];
}

__global__ void finalize(const float* __restrict__ sums, float* __restrict__ out) {
    __shared__ float sh[2];
    const int t = threadIdx.x;  // 128
    float v = sums[t];
    #pragma unroll
    for (int k = 1; k < 64; k <<= 1) v += __shfl_xor(v, k);
    if ((t & 63) == 0) sh[t >> 6] = v;
    __syncthreads();
    if (t == 0) out[0] = (sh[0] + sh[1]) * (1.0f / (10.f * BATCH * KK));
}

extern "C" void kernel_launch(void* const* d_in, const int* in_sizes, int n_in,
                              void* d_out, int out_size, void* d_ws, size_t ws_size,
                              hipStream_t stream) {
    const float* img = (const float*)d_in[0];
    const float* pc = (const float*)d_in[1];
    const float* dmap = (const float*)d_in[2];
    float* out = (float*)d_out;
    float* wsf = (float*)d_ws;

    prep<<<dim3(256), dim3(256), 0, stream>>>(img, pc, wsf);
    fused_main<<<dim3(1024), dim3(256), 0, stream>>>(dmap, out + 1, wsf);
    reduce_lse<<<dim3(128), dim3(256), 0, stream>>>(wsf, wsf + SUMS_OFF);
    finalize<<<dim3(1), dim3(128), 0, stream>>>(wsf + SUMS_OFF, out);
}